// Round 1
// baseline (1333.689 us; speedup 1.0000x reference)
//
#include <hip/hip_runtime.h>
#include <math.h>

// ---------------- problem constants ----------------
#define B_  64
#define S_  128
#define H_  128
#define D_  300
#define L_  20
#define G4  512                 // 4*H
#define SH  (S_*H_)             // 16384
#define BSH ((size_t)B_*SH)     // 1048576
#define EPSV 1e-8f
#define PAD 132                 // 128 + 4: float4-aligned row stride, breaks bank conflicts

// monotonic float<->uint mapping for atomicMax on floats (handles negatives)
__device__ __forceinline__ unsigned fmap(float f){
  unsigned u = __float_as_uint(f);
  return (u & 0x80000000u) ? ~u : (u | 0x80000000u);
}
__device__ __forceinline__ float funmap(unsigned u){
  return __uint_as_float((u & 0x80000000u) ? (u & 0x7fffffffu) : ~u);
}
__device__ __forceinline__ float sigmf(float x){ return 1.f/(1.f+expf(-x)); }

// ---------------- embedding gather ----------------
// grid (B*S, 2), block 256
__global__ void k_embed(const float* __restrict__ emb, const int* __restrict__ p,
                        const int* __restrict__ h, float* __restrict__ x1,
                        float* __restrict__ x2)
{
  int row = blockIdx.x;
  const int* idx = blockIdx.y ? h : p;
  float* x = blockIdx.y ? x2 : x1;
  int tok = idx[row];
  const float* src = emb + (size_t)tok * D_;
  float* dst = x + (size_t)row * D_;
  for (int d = threadIdx.x; d < D_; d += blockDim.x) dst[d] = src[d];
}

// ---------------- generic GEMM: C = A(M,K) * W(N,K)^T + bias ----------------
// grid (M/64, N/64, 4); q selects A (x1/x2 or aggr1/aggr2) and W/bias (fwd/bwd)
__global__ __launch_bounds__(256) void gemm_abt(
    const float* __restrict__ A0, const float* __restrict__ A1,
    const float* __restrict__ W0, const float* __restrict__ W1,
    const float* __restrict__ b0, const float* __restrict__ b1,
    float* __restrict__ Cbase, int M, int N, int K)
{
  int q = blockIdx.z;
  const float* A = (q >> 1) ? A1 : A0;
  const float* W = (q & 1) ? W1 : W0;
  const float* bias = (q & 1) ? b1 : b0;
  float* Cm = Cbase + (size_t)q * M * N;

  __shared__ __align__(16) float As[16][68];  // [k][m], stride 68 -> 16B aligned rows
  __shared__ __align__(16) float Ws[16][68];  // [k][n]
  int t = threadIdx.x, tx = t & 15, ty = t >> 4;
  int m0 = blockIdx.x * 64, n0 = blockIdx.y * 64;
  float acc[4][4] = {};

  for (int k0 = 0; k0 < K; k0 += 16) {
    #pragma unroll
    for (int i = 0; i < 4; i++) {
      int idx = t + 256 * i, r = idx >> 4, kk = idx & 15;
      int gk = k0 + kk;
      As[kk][r] = (gk < K) ? A[(size_t)(m0 + r) * K + gk] : 0.f;
      Ws[kk][r] = (gk < K) ? W[(size_t)(n0 + r) * K + gk] : 0.f;
    }
    __syncthreads();
    #pragma unroll
    for (int kk = 0; kk < 16; kk++) {
      float4 av = *(const float4*)&As[kk][ty * 4];
      float4 wv = *(const float4*)&Ws[kk][tx * 4];
      float a[4] = {av.x, av.y, av.z, av.w};
      float w[4] = {wv.x, wv.y, wv.z, wv.w};
      #pragma unroll
      for (int i = 0; i < 4; i++)
        #pragma unroll
        for (int j = 0; j < 4; j++) acc[i][j] += a[i] * w[j];
    }
    __syncthreads();
  }
  #pragma unroll
  for (int i = 0; i < 4; i++) {
    int gm = m0 + ty * 4 + i;
    int gn = n0 + tx * 4;
    float4 o = make_float4(acc[i][0] + bias[gn], acc[i][1] + bias[gn + 1],
                           acc[i][2] + bias[gn + 2], acc[i][3] + bias[gn + 3]);
    *(float4*)&Cm[(size_t)gm * N + gn] = o;
  }
}

// ---------------- LSTM scan ----------------
// grid (B, 4): q = (seq<<1)|dir. xg layout: [q][b][t][512]. out: [q][b][t][128].
// thread j holds w_hh row j in registers; h,c in LDS.
__global__ __launch_bounds__(512) void k_lstm(const float* __restrict__ xg,
    const float* __restrict__ whhF, const float* __restrict__ whhB,
    float* __restrict__ hs)
{
  int b = blockIdx.x, q = blockIdx.y, dir = q & 1;
  const float* whh = dir ? whhB : whhF;
  const float* xgq = xg + ((size_t)(q * B_ + b)) * (S_ * G4);
  float* out = hs + ((size_t)(q * B_ + b)) * SH;
  int j = threadIdx.x;

  float w[128];
  #pragma unroll
  for (int k = 0; k < 128; k += 4) {
    float4 v = *(const float4*)(whh + (size_t)j * 128 + k);
    w[k] = v.x; w[k + 1] = v.y; w[k + 2] = v.z; w[k + 3] = v.w;
  }
  __shared__ __align__(16) float hsm[128];
  __shared__ float csm[128];
  __shared__ float gsm[512];
  if (j < 128) { hsm[j] = 0.f; csm[j] = 0.f; }
  __syncthreads();

  for (int st = 0; st < S_; st++) {
    int tt = dir ? (S_ - 1 - st) : st;
    float acc = xgq[(size_t)tt * G4 + j];
    #pragma unroll
    for (int k = 0; k < 128; k += 4) {
      float4 hv = *(const float4*)&hsm[k];   // broadcast reads
      acc += w[k] * hv.x + w[k + 1] * hv.y + w[k + 2] * hv.z + w[k + 3] * hv.w;
    }
    gsm[j] = acc;
    __syncthreads();
    if (j < 128) {
      float ig = sigmf(gsm[j]);
      float fg = sigmf(gsm[128 + j]);
      float gg = tanhf(gsm[256 + j]);
      float og = sigmf(gsm[384 + j]);
      float c = fg * csm[j] + ig * gg;
      float hn = og * tanhf(c);
      csm[j] = c; hsm[j] = hn;
      out[(size_t)tt * H_ + j] = hn;
    }
    __syncthreads();
  }
}

// ---------------- full matching ----------------
// grid (B,4): q 0:(c1f vs c2f[last], w1)->ag1  1:(c1b,c2b,w2)->ag1
//             2:(c2f vs c1f[last], w1)->ag2  3:(c2b,c1b,w2)->ag2
__global__ __launch_bounds__(256) void k_full(const float* __restrict__ C,
    const float* __restrict__ w1, const float* __restrict__ w2,
    float* __restrict__ ag1, float* __restrict__ ag2)
{
  int b = blockIdx.x, q = blockIdx.y, dir = q & 1;
  const float* p1  = C + (size_t)q * BSH + (size_t)b * SH;
  const float* p2l = C + (size_t)((q + 2) & 3) * BSH + (size_t)b * SH + (size_t)(S_ - 1) * H_;
  const float* w = dir ? w2 : w1;
  float* out = (q < 2 ? ag1 : ag2) + (size_t)b * S_ * 160;

  __shared__ float ws2[H_][L_];
  __shared__ float p2s[H_];
  __shared__ float n2s[L_];
  int t = threadIdx.x;
  for (int i = t; i < H_ * L_; i += 256) { float v = w[i]; ws2[i / L_][i % L_] = v * v; }
  if (t < H_) p2s[t] = p2l[t];
  __syncthreads();
  if (t < L_) {
    float s = 0.f;
    for (int hh = 0; hh < H_; hh++) { float v = p2s[hh]; s += v * v * ws2[hh][t]; }
    n2s[t] = sqrtf(s);
  }
  __syncthreads();
  for (int i = t; i < S_ * L_; i += 256) {
    int s = i / L_, l = i % L_;
    const float* pr = p1 + (size_t)s * H_;
    float dot = 0.f, n1 = 0.f;
    for (int hh = 0; hh < H_; hh++) {
      float a = pr[hh], ww = ws2[hh][l];
      dot += a * p2s[hh] * ww;
      n1 += a * a * ww;
    }
    n1 = sqrtf(n1);
    out[(size_t)s * 160 + dir * L_ + l] = dot / (fmaxf(n1, EPSV) * fmaxf(n2s[l], EPSV));
  }
}

// ---------------- maxpool matching ----------------
// grid (B, L, 2dir). One cos matrix serves both p1 (row-max) and p2 (col-max).
__global__ __launch_bounds__(256) void k_maxpool(const float* __restrict__ C,
    const float* __restrict__ w3, const float* __restrict__ w4,
    float* __restrict__ ag1, float* __restrict__ ag2)
{
  int b = blockIdx.x, l = blockIdx.y, dir = blockIdx.z;
  const float* p1 = C + (size_t)(0 + dir) * BSH + (size_t)b * SH;  // c1f/c1b
  const float* p2 = C + (size_t)(2 + dir) * BSH + (size_t)b * SH;  // c2f/c2b
  const float* w = dir ? w4 : w3;

  __shared__ __align__(16) float a1[S_][PAD];
  __shared__ __align__(16) float a2[S_][PAD];
  __shared__ float n1s[S_], n2s[S_];
  __shared__ unsigned mx1[S_], mx2[S_];
  int t = threadIdx.x;

  for (int i = t; i < SH; i += 256) {
    int ss = i >> 7, hh = i & 127;
    float wl = w[hh * L_ + l];
    a1[ss][hh] = p1[i] * wl;
    a2[ss][hh] = p2[i] * wl;
  }
  if (t < S_) { mx1[t] = 0u; mx2[t] = 0u; }
  __syncthreads();
  if (t < S_) {
    float s = 0.f;
    for (int hh = 0; hh < H_; hh++) { float v = a1[t][hh]; s += v * v; }
    n1s[t] = sqrtf(s);
  } else {
    int tt = t - S_;
    float s = 0.f;
    for (int hh = 0; hh < H_; hh++) { float v = a2[tt][hh]; s += v * v; }
    n2s[tt] = sqrtf(s);
  }
  __syncthreads();

  #pragma unroll
  for (int it = 0; it < 4; it++) {
    int tile = t + 256 * it;
    int ss = tile >> 5, tt = tile & 31;
    float acc[4][4] = {};
    for (int hh = 0; hh < H_; hh += 4) {
      float4 x[4], y[4];
      #pragma unroll
      for (int i = 0; i < 4; i++) x[i] = *(const float4*)&a1[ss + 32 * i][hh];
      #pragma unroll
      for (int j = 0; j < 4; j++) y[j] = *(const float4*)&a2[tt + 32 * j][hh];
      #pragma unroll
      for (int i = 0; i < 4; i++)
        #pragma unroll
        for (int j = 0; j < 4; j++)
          acc[i][j] += x[i].x * y[j].x + x[i].y * y[j].y + x[i].z * y[j].z + x[i].w * y[j].w;
    }
    float rmax[4] = {-3.4e38f, -3.4e38f, -3.4e38f, -3.4e38f};
    float cmax[4] = {-3.4e38f, -3.4e38f, -3.4e38f, -3.4e38f};
    #pragma unroll
    for (int i = 0; i < 4; i++)
      #pragma unroll
      for (int j = 0; j < 4; j++) {
        float deno = n1s[ss + 32 * i] * n2s[tt + 32 * j];
        float cs = acc[i][j] / (deno > EPSV ? deno : EPSV);   // safe_div
        rmax[i] = fmaxf(rmax[i], cs);
        cmax[j] = fmaxf(cmax[j], cs);
      }
    #pragma unroll
    for (int i = 0; i < 4; i++) atomicMax(&mx1[ss + 32 * i], fmap(rmax[i]));
    #pragma unroll
    for (int j = 0; j < 4; j++) atomicMax(&mx2[tt + 32 * j], fmap(cmax[j]));
  }
  __syncthreads();
  if (t < S_)
    ag1[(size_t)b * S_ * 160 + (size_t)t * 160 + 40 + dir * L_ + l] = funmap(mx1[t]);
  else {
    int tt = t - S_;
    ag2[(size_t)b * S_ * 160 + (size_t)tt * 160 + 40 + dir * L_ + l] = funmap(mx2[tt]);
  }
}

// ---------------- alpha (plain cosine matrix) ----------------
// grid (B, 2dir). alpha[dir][b][s][t]
__global__ __launch_bounds__(256) void k_alpha(const float* __restrict__ C,
                                               float* __restrict__ alpha)
{
  int b = blockIdx.x, dir = blockIdx.y;
  const float* p1 = C + (size_t)(0 + dir) * BSH + (size_t)b * SH;
  const float* p2 = C + (size_t)(2 + dir) * BSH + (size_t)b * SH;
  __shared__ __align__(16) float a1[S_][PAD];
  __shared__ __align__(16) float a2[S_][PAD];
  __shared__ float n1s[S_], n2s[S_];
  int t = threadIdx.x;
  for (int i = t; i < SH; i += 256) {
    int ss = i >> 7, hh = i & 127;
    a1[ss][hh] = p1[i];
    a2[ss][hh] = p2[i];
  }
  __syncthreads();
  if (t < S_) {
    float s = 0.f;
    for (int hh = 0; hh < H_; hh++) { float v = a1[t][hh]; s += v * v; }
    n1s[t] = sqrtf(s);
  } else {
    int tt = t - S_;
    float s = 0.f;
    for (int hh = 0; hh < H_; hh++) { float v = a2[tt][hh]; s += v * v; }
    n2s[tt] = sqrtf(s);
  }
  __syncthreads();
  float* out = alpha + ((size_t)dir * B_ + b) * SH;
  #pragma unroll
  for (int it = 0; it < 4; it++) {
    int tile = t + 256 * it;
    int ss = tile >> 5, tt = tile & 31;
    float acc[4][4] = {};
    for (int hh = 0; hh < H_; hh += 4) {
      float4 x[4], y[4];
      #pragma unroll
      for (int i = 0; i < 4; i++) x[i] = *(const float4*)&a1[ss + 32 * i][hh];
      #pragma unroll
      for (int j = 0; j < 4; j++) y[j] = *(const float4*)&a2[tt + 32 * j][hh];
      #pragma unroll
      for (int i = 0; i < 4; i++)
        #pragma unroll
        for (int j = 0; j < 4; j++)
          acc[i][j] += x[i].x * y[j].x + x[i].y * y[j].y + x[i].z * y[j].z + x[i].w * y[j].w;
    }
    #pragma unroll
    for (int i = 0; i < 4; i++)
      #pragma unroll
      for (int j = 0; j < 4; j++) {
        float deno = n1s[ss + 32 * i] * n2s[tt + 32 * j];
        out[(size_t)(ss + 32 * i) * S_ + (tt + 32 * j)] = acc[i][j] / (deno > EPSV ? deno : EPSV);
      }
  }
}

// ---------------- attentive matching ----------------
// grid (B, 4): q 0:(p1=c1f, m2=c2f, alpha_f)   1:(c1b,c2b,alpha_b)  -> ag1
//              2:(p1=c2f, m2=c1f, alpha_f^T)  3:(c2b,c1b,alpha_b^T) -> ag2
__global__ __launch_bounds__(256) void k_att(const float* __restrict__ C,
    const float* __restrict__ alpha,
    const float* __restrict__ w5, const float* __restrict__ w6,
    const float* __restrict__ w7, const float* __restrict__ w8,
    float* __restrict__ ag1, float* __restrict__ ag2)
{
  int b = blockIdx.x, q = blockIdx.y, dir = q & 1;
  const float* p1  = C + (size_t)q * BSH + (size_t)b * SH;
  const float* m2g = C + (size_t)((q + 2) & 3) * BSH + (size_t)b * SH;
  const float* wa = dir ? w6 : w5;
  const float* wm = dir ? w8 : w7;
  const float* ain = alpha + ((size_t)dir * B_ + b) * SH;
  float* out = (q < 2 ? ag1 : ag2) + (size_t)b * S_ * 160;
  bool tr = (q >= 2);

  __shared__ __align__(16) float A[S_][PAD];    // alpha_eff[s][t], later resultant[s][h]
  __shared__ __align__(16) float M2T[H_][PAD];  // m2 transposed: [h][t]
  __shared__ float wa2[H_][L_];
  __shared__ float wm2[H_][L_];
  __shared__ float rowsum[S_];
  __shared__ int   midx[S_];
  __shared__ float p1r[H_];
  int t = threadIdx.x;

  for (int i = t; i < SH; i += 256) {
    int ss = i >> 7, tt2 = i & 127;
    float av = ain[i];
    if (tr) A[tt2][ss] = av; else A[ss][tt2] = av;
    M2T[tt2][ss] = m2g[i];
  }
  for (int i = t; i < H_ * L_; i += 256) {
    float v = wa[i]; wa2[i / L_][i % L_] = v * v;
    float u = wm[i]; wm2[i / L_][i % L_] = u * u;
  }
  __syncthreads();
  // rowsum + first-argmax per s (serial per lane preserves jnp.argmax tie order)
  if (t < S_) {
    float sum = 0.f, best = -3.4e38f; int bi = 0;
    for (int k = 0; k < S_; k++) {
      float v = A[t][k];
      sum += v;
      if (v > best) { best = v; bi = k; }
    }
    rowsum[t] = sum; midx[t] = bi;
  }
  __syncthreads();
  // resultant = (A @ M2) / rowsum : 4x4 register tiles, then overwrite A
  float acc[4][4][4];
  #pragma unroll
  for (int it = 0; it < 4; it++) {
    int tile = t + 256 * it;
    int ss = tile >> 5, hh = tile & 31;
    #pragma unroll
    for (int i = 0; i < 4; i++)
      #pragma unroll
      for (int j = 0; j < 4; j++) acc[it][i][j] = 0.f;
    for (int k = 0; k < S_; k += 4) {
      float4 xa[4], yb[4];
      #pragma unroll
      for (int i = 0; i < 4; i++) xa[i] = *(const float4*)&A[ss + 32 * i][k];
      #pragma unroll
      for (int j = 0; j < 4; j++) yb[j] = *(const float4*)&M2T[hh + 32 * j][k];
      #pragma unroll
      for (int i = 0; i < 4; i++)
        #pragma unroll
        for (int j = 0; j < 4; j++)
          acc[it][i][j] += xa[i].x * yb[j].x + xa[i].y * yb[j].y + xa[i].z * yb[j].z + xa[i].w * yb[j].w;
    }
  }
  __syncthreads();
  #pragma unroll
  for (int it = 0; it < 4; it++) {
    int tile = t + 256 * it;
    int ss = tile >> 5, hh = tile & 31;
    #pragma unroll
    for (int i = 0; i < 4; i++)
      #pragma unroll
      for (int j = 0; j < 4; j++)
        A[ss + 32 * i][hh + 32 * j] = acc[it][i][j] / rowsum[ss + 32 * i];
  }
  __syncthreads();

  // per-s weighted cosines: att (resultant vs p1, wa) and attm (m2[midx] vs p1, wm)
  for (int s = 0; s < S_; s++) {
    if (t < H_) p1r[t] = p1[(size_t)s * H_ + t];
    __syncthreads();
    if (t < 8 * L_) {
      int l = t >> 3, p = t & 7;
      int mi = midx[s];
      float dA = 0.f, naA = 0.f, nbA = 0.f, dM = 0.f, naM = 0.f, nbM = 0.f;
      #pragma unroll
      for (int k = 0; k < 16; k++) {
        int hh = p + 8 * k;
        float bv = p1r[hh];
        float avA = A[s][hh];
        float w2A = wa2[hh][l];
        dA += avA * bv * w2A; naA += avA * avA * w2A; nbA += bv * bv * w2A;
        float avM = M2T[hh][mi];
        float w2M = wm2[hh][l];
        dM += avM * bv * w2M; naM += avM * avM * w2M; nbM += bv * bv * w2M;
      }
      #pragma unroll
      for (int m = 1; m < 8; m <<= 1) {
        dA += __shfl_xor(dA, m, 64); naA += __shfl_xor(naA, m, 64); nbA += __shfl_xor(nbA, m, 64);
        dM += __shfl_xor(dM, m, 64); naM += __shfl_xor(naM, m, 64); nbM += __shfl_xor(nbM, m, 64);
      }
      if (p == 0) {
        out[(size_t)s * 160 + 80 + dir * L_ + l]  = dA / (fmaxf(sqrtf(naA), EPSV) * fmaxf(sqrtf(nbA), EPSV));
        out[(size_t)s * 160 + 120 + dir * L_ + l] = dM / (fmaxf(sqrtf(naM), EPSV) * fmaxf(sqrtf(nbM), EPSV));
      }
    }
    __syncthreads();
  }
}

// ---------------- final MLP ----------------
// grid (B), block 256
__global__ __launch_bounds__(256) void k_final(const float* __restrict__ Cc,
    const float* __restrict__ pW1, const float* __restrict__ pb1,
    const float* __restrict__ pW2, const float* __restrict__ pb2,
    float* __restrict__ out)
{
  int b = blockIdx.x, t = threadIdx.x;
  __shared__ float cat[512];
  __shared__ float hid[256];
  if (t < 128) {
    cat[t]       = Cc[(size_t)(0 * B_ + b) * SH + (size_t)(S_ - 1) * H_ + t];
    cat[128 + t] = Cc[(size_t)(1 * B_ + b) * SH + (size_t)(S_ - 1) * H_ + t];
    cat[256 + t] = Cc[(size_t)(2 * B_ + b) * SH + (size_t)(S_ - 1) * H_ + t];
    cat[384 + t] = Cc[(size_t)(3 * B_ + b) * SH + (size_t)(S_ - 1) * H_ + t];
  }
  __syncthreads();
  float a = pb1[t];
  for (int k = 0; k < 512; k++) a += cat[k] * pW1[(size_t)t * 512 + k];
  hid[t] = fmaxf(a, 0.f);
  __syncthreads();
  if (t < 3) {
    float o = pb2[t];
    for (int k = 0; k < 256; k++) o += hid[k] * pW2[(size_t)t * 256 + k];
    out[(size_t)b * 3 + t] = o;
  }
}

// ---------------- launch ----------------
extern "C" void kernel_launch(void* const* d_in, const int* in_sizes, int n_in,
                              void* d_out, int out_size, void* d_ws, size_t ws_size,
                              hipStream_t stream)
{
  const float* emb    = (const float*)d_in[0];
  const float* cwih_f = (const float*)d_in[1];
  const float* cwhh_f = (const float*)d_in[2];
  const float* cb_f   = (const float*)d_in[3];
  const float* cwih_b = (const float*)d_in[4];
  const float* cwhh_b = (const float*)d_in[5];
  const float* cb_b   = (const float*)d_in[6];
  const float* awih_f = (const float*)d_in[7];
  const float* awhh_f = (const float*)d_in[8];
  const float* ab_f   = (const float*)d_in[9];
  const float* awih_b = (const float*)d_in[10];
  const float* awhh_b = (const float*)d_in[11];
  const float* ab_b   = (const float*)d_in[12];
  const float* pW1    = (const float*)d_in[13];
  const float* pb1    = (const float*)d_in[14];
  const float* pW2    = (const float*)d_in[15];
  const float* pb2    = (const float*)d_in[16];
  const int*   pidx   = (const int*)d_in[17];
  const int*   hidx   = (const int*)d_in[18];
  const float* w1 = (const float*)d_in[19];
  const float* w2 = (const float*)d_in[20];
  const float* w3 = (const float*)d_in[21];
  const float* w4 = (const float*)d_in[22];
  const float* w5 = (const float*)d_in[23];
  const float* w6 = (const float*)d_in[24];
  const float* w7 = (const float*)d_in[25];
  const float* w8 = (const float*)d_in[26];

  float* ws = (float*)d_ws;
  // region layout (floats), with phase-safe aliasing:
  //   XG   [0, 16777216)              : 4x(8192x512) projections (ctx, then agg)
  //   X1/X2[16777216, +4915200)       : embeddings; after ctx-proj reused as:
  //       ALPH = X1 (2x64x128x128 = 2097152), AG1/AG2 after it (2x64x128x160)
  //   CC   [21692416, +4194304)       : 4x(B,S,H) hidden states (ctx, then agg)
  float* XG   = ws;
  float* X1   = ws + 16777216;
  float* X2   = X1 + 2457600;
  float* ALPH = X1;
  float* AG1  = ws + 16777216 + 2097152;
  float* AG2  = AG1 + (size_t)B_ * S_ * 160;
  float* CC   = ws + 21692416;

  // 1) embedding gather
  k_embed<<<dim3(B_ * S_, 2), 256, 0, stream>>>(emb, pidx, hidx, X1, X2);
  // 2) ctx input projections (4 GEMMs in grid.z)
  gemm_abt<<<dim3(128, 8, 4), 256, 0, stream>>>(X1, X2, cwih_f, cwih_b, cb_f, cb_b,
                                                XG, B_ * S_, G4, D_);
  // 3) ctx BiLSTM scans -> c1f,c1b,c2f,c2b
  k_lstm<<<dim3(B_, 4), 512, 0, stream>>>(XG, cwhh_f, cwhh_b, CC);
  // 4) full matching (cols 0..39)
  k_full<<<dim3(B_, 4), 256, 0, stream>>>(CC, w1, w2, AG1, AG2);
  // 5) maxpool matching (cols 40..79)
  k_maxpool<<<dim3(B_, L_, 2), 256, 0, stream>>>(CC, w3, w4, AG1, AG2);
  // 6) attention cosine matrices
  k_alpha<<<dim3(B_, 2), 256, 0, stream>>>(CC, ALPH);
  // 7) attentive + attentive-max matching (cols 80..159)
  k_att<<<dim3(B_, 4), 256, 0, stream>>>(CC, ALPH, w5, w6, w7, w8, AG1, AG2);
  // 8) agg input projections
  gemm_abt<<<dim3(128, 8, 4), 256, 0, stream>>>(AG1, AG2, awih_f, awih_b, ab_f, ab_b,
                                                XG, B_ * S_, G4, 8 * L_);
  // 9) agg BiLSTM scans
  k_lstm<<<dim3(B_, 4), 512, 0, stream>>>(XG, awhh_f, awhh_b, CC);
  // 10) final MLP
  k_final<<<dim3(B_), 256, 0, stream>>>(CC, pW1, pb1, pW2, pb2, (float*)d_out);
}